// Round 3
// baseline (169.767 us; speedup 1.0000x reference)
//
#include <hip/hip_runtime.h>
#include <hip/hip_bf16.h>
#include <math.h>

#define HW    16384
#define Bsz   4
#define CIN   32
#define COUT  64
#define RED   16
#define KKN   49
#define GG    4
#define PW    134           // padded width/height (128 + 2*3)
#define NHALO 25152         // 16 planes * 1572 halo pixels
#define NZB   99            // halo-zero blocks
#define NPXB  1024          // k1 pixel blocks (64 px each)

typedef __hip_bfloat16 bf16;
typedef __attribute__((ext_vector_type(8))) short bf16x8;   // 8 bf16 = 4 VGPR
typedef __attribute__((ext_vector_type(4))) float f32x4;

__device__ __forceinline__ float gelu_f(float x) {
    return 0.5f * x * (1.0f + erff(x * 0.70710678118654752f));
}
__device__ __forceinline__ void unpack_bf2(unsigned u, float& lo, float& hi) {
    lo = __uint_as_float(u << 16);
    hi = __uint_as_float(u & 0xffff0000u);
}
__device__ __forceinline__ unsigned pack_bf2(float lo, float hi) {
    unsigned a = __float_as_uint(lo), b = __float_as_uint(hi);
    a += 0x7fff + ((a >> 16) & 1);
    b += 0x7fff + ((b >> 16) & 1);
    return (a >> 16) | (b & 0xffff0000u);
}
__device__ __forceinline__ unsigned short bf16r(float v) {
    unsigned a = __float_as_uint(v);
    a += 0x7fff + ((a >> 16) & 1);
    return (unsigned short)(a >> 16);
}

// ---- workspace layout (bytes) ----
#define OFF_RBUF  9437184
#define OFF_PAR   22020096
#define OFF_XBF   22085632          // par region is 64 KB
// par region: float index offsets
#define PSHC_F 16
#define PSMV_F 80
#define PSC1_F 144
#define PSH1_F 208
// par region: byte offset for bf16 table
#define BCAT 12288                  // wcat ushort[64][96]

// K1 (standalone): blocks 0..NPXB-1 do conv1+reduce for 64 px each, building
// all weight fragments inline from raw weights (bit-identical bf16r math).
// Blocks NPXB..NPXB+NZB-1 zero the x1pad halo; last block preps wcat/par for k34.
__global__ __launch_bounds__(256, 4) void k1_all(
    const float* __restrict__ x, const float* __restrict__ w1,
    const float* __restrict__ wr, const float* __restrict__ gr,
    const float* __restrict__ br, const float* __restrict__ mr,
    const float* __restrict__ vr,
    const float* __restrict__ g1, const float* __restrict__ b1,
    const float* __restrict__ m1, const float* __restrict__ v1,
    const float* __restrict__ w2, const float* __restrict__ g2,
    const float* __restrict__ b2, const float* __restrict__ m2,
    const float* __restrict__ v2,
    const float* __restrict__ wm, const float* __restrict__ bmap,
    const float* __restrict__ gm, const float* __restrict__ betam,
    const float* __restrict__ mm, const float* __restrict__ vm,
    char* __restrict__ parb, unsigned* __restrict__ x1pad,
    unsigned short* __restrict__ xbf, float* __restrict__ rbuf)
{
    __shared__ float x1f[4][16][65];
    int bid = blockIdx.x, t = threadIdx.x;

    if (bid >= NPXB) {
        int hb = bid - NPXB;
        if (hb < NZB) {
            // halo-only zero of x1pad (interior overwritten by px blocks)
            unsigned i = (unsigned)hb * 256u + (unsigned)t;
            if (i < NHALO) {
                unsigned plane = i / 1572u;
                unsigned rem = i - plane * 1572u;
                unsigned row, col;
                if (rem < 804u) {
                    unsigned rr = rem / 134u;
                    col = rem - rr * 134u;
                    row = rr < 3u ? rr : rr + 128u;
                } else {
                    unsigned r2 = rem - 804u;
                    unsigned rr = r2 / 6u;
                    unsigned cc = r2 - rr * 6u;
                    row = rr + 3u;
                    col = cc < 3u ? cc : cc + 128u;
                }
                uint4* q = (uint4*)x1pad + ((size_t)(plane * PW + row) * PW + col) * 2;
                q[0] = make_uint4(0u, 0u, 0u, 0u);
                q[1] = make_uint4(0u, 0u, 0u, 0u);
            }
        } else {
            // wcat + par prep (consumed only by k34, which launches after)
            float* parf = (float*)parb;
            unsigned short* wcat = (unsigned short*)(parb + BCAT);
            for (int i = t; i < 64 * 96; i += 256) {
                int o = i / 96, c = i - o * 96;
                float v;
                if (c < 64) {
                    float s2 = g2[o] * rsqrtf(v2[o] + 1e-5f);
                    float sm = gm[o] * rsqrtf(vm[o] + 1e-5f);
                    v = w2[o * COUT + c] * (s2 / sm);
                } else {
                    v = wm[o * CIN + (c - 64)];
                }
                wcat[i] = bf16r(v);
            }
            if (t < 64) {
                float s2 = g2[t] * rsqrtf(v2[t] + 1e-5f);
                float sm = gm[t] * rsqrtf(vm[t] + 1e-5f);
                parf[PSHC_F + t] = (b2[t] - m2[t] * s2) + (betam[t] + (bmap[t] - mm[t]) * sm);
                parf[PSMV_F + t] = sm;
                float s1 = g1[t] * rsqrtf(v1[t] + 1e-5f);
                parf[PSC1_F + t] = s1;
                parf[PSH1_F + t] = b1[t] - m1[t] * s1;
            }
        }
        return;
    }

    // ---- pixel block: conv1 MFMA -> gelu -> x1pad + xbf; reduce MFMA -> rbuf
    int lane = t & 63;
    int wave = t >> 6;
    int m15 = lane & 15, quad = lane >> 4;
    int base_gpx = bid * 64 + wave * 16;            // 64 px per block, 16 per wave
    int b   = base_gpx >> 14;
    int px0 = base_gpx & (HW - 1);

    // A-frag: load 8 channels (quad*8..+7) of px base_gpx+m15 from x, pack bf16
    int gpx = base_gpx + m15;
    int p   = gpx & (HW - 1);
    unsigned apk[4];
#pragma unroll
    for (int d = 0; d < 4; ++d) {
        float lo = x[((size_t)(b * CIN + quad * 8 + 2 * d)) * HW + p];
        float hi = x[((size_t)(b * CIN + quad * 8 + 2 * d + 1)) * HW + p];
        apk[d] = pack_bf2(lo, hi);
    }
    union BU { uint4 q; bf16x8 v; };
    BU au; au.q = make_uint4(apk[0], apk[1], apk[2], apk[3]);
    bf16x8 Af = au.v;
    // persist xbf for k34 (identical values to old k0 build)
    *(uint4*)&xbf[(size_t)gpx * 32 + quad * 8] = au.q;

    // conv1: B-frags built inline from w1 (bf16r identical to old w1b)
    f32x4 acc[4];
#pragma unroll
    for (int nt = 0; nt < 4; ++nt) {
        int o = nt * 16 + m15;
        unsigned bpk[4];
#pragma unroll
        for (int d = 0; d < 4; ++d) {
            float lo = w1[o * CIN + quad * 8 + 2 * d];
            float hi = w1[o * CIN + quad * 8 + 2 * d + 1];
            bpk[d] = pack_bf2(lo, hi);
        }
        BU bu; bu.q = make_uint4(bpk[0], bpk[1], bpk[2], bpk[3]);
        f32x4 z = {0.f, 0.f, 0.f, 0.f};
        acc[nt] = __builtin_amdgcn_mfma_f32_16x16x32_bf16(Af, bu.v, z, 0, 0, 0);
    }
    // gelu + stage to LDS (D: row px=quad*4+reg, col o=nt*16+m15)
#pragma unroll
    for (int nt = 0; nt < 4; ++nt)
#pragma unroll
        for (int reg = 0; reg < 4; ++reg)
            x1f[wave][quad * 4 + reg][nt * 16 + m15] = gelu_f(acc[nt][reg]);

    __syncthreads();

    // x1pad store: lane l -> px=l>>2, group g=l&3 (16 ch contiguous bf16)
    {
        int pxl = lane >> 2, g = lane & 3;
        int pp = px0 + pxl, h = pp >> 7, w = pp & 127;
        unsigned pk[8];
#pragma unroll
        for (int d = 0; d < 8; ++d)
            pk[d] = pack_bf2(x1f[wave][pxl][g * 16 + 2 * d],
                             x1f[wave][pxl][g * 16 + 2 * d + 1]);
        unsigned* xo = x1pad +
            ((size_t)((b * GG + g) * PW + (h + 3)) * PW + (w + 3)) * 8;
        *(uint4*)xo       = make_uint4(pk[0], pk[1], pk[2], pk[3]);
        *(uint4*)(xo + 4) = make_uint4(pk[4], pk[5], pk[6], pk[7]);
    }

    // reduce: A[m=px][k=c] from LDS (bf16 repack), B[k=c][n=j] from wr*sc inline
    float sc  = gr[m15] * rsqrtf(vr[m15] + 1e-5f);
    float rsh = br[m15] - mr[m15] * sc;
    f32x4 racc = {0.f, 0.f, 0.f, 0.f};
#pragma unroll
    for (int kt = 0; kt < 2; ++kt) {
        bf16x8 A2, B2;
#pragma unroll
        for (int j = 0; j < 8; ++j) {
            A2[j] = (short)bf16r(x1f[wave][m15][kt * 32 + quad * 8 + j]);
            B2[j] = (short)bf16r(wr[m15 * 64 + kt * 32 + quad * 8 + j] * sc);
        }
        racc = __builtin_amdgcn_mfma_f32_16x16x32_bf16(A2, B2, racc, 0, 0, 0);
    }
    // D: row px=quad*4+reg, col j=m15. relu + shift, store rbuf [px][j16]
#pragma unroll
    for (int reg = 0; reg < 4; ++reg) {
        int gp = base_gpx + quad * 4 + reg;
        rbuf[(size_t)gp * 16 + m15] = fmaxf(racc[reg] + rsh, 0.f);
    }
}

// K34: fused involution (phase 1, row-pair) + conv2/skip MFMA (phase 2).
// Block = 128 px tile (rows 2R,2R+1 x 64 cols) x 4 groups; 256 threads.
// Phase 1: thread=(col, g) computes BOTH rows; 7x7 windows share 6/8 rows ->
// tap loads 28/px instead of 49/px, unpack shared. Tap order per px unchanged
// (k=0..48 sequential) -> bit-identical accumulation.
__global__ __launch_bounds__(256, 2) void k34_fused(
    const unsigned* __restrict__ x1pad, const float* __restrict__ rbuf,
    const float* __restrict__ wsp, const float* __restrict__ bsp,
    const char* __restrict__ parb, const unsigned short* __restrict__ xbf,
    float* __restrict__ out)
{
    __shared__ unsigned short x2t[2][64][88];

    const float* par = (const float*)parb;
    int t = threadIdx.x;
    int b    = blockIdx.x >> 7;                     // 128 tiles per batch
    int tile = blockIdx.x & 127;
    int R  = tile >> 1;                             // row pair index (0..63)
    int Cc = tile & 1;                              // 64-col half (0..1)
    int h0 = 2 * R;

    // ---- phase 1: involution, 64 cols x 2 rows x 4 groups ----
    {
        int c = t & 63;
        int g = __builtin_amdgcn_readfirstlane(t >> 6);   // wave-uniform
        int w0 = Cc * 64 + c;
        int p0 = h0 * 128 + w0;                     // row h0 pixel
        int bg = b * GG + g;

        float r0[RED], r1[RED];
        {
            const float4* rp = (const float4*)&rbuf[((size_t)b * HW + p0) * 16];
            float4 a0 = rp[0], a1 = rp[1], a2 = rp[2], a3 = rp[3];
            r0[0]=a0.x; r0[1]=a0.y; r0[2]=a0.z; r0[3]=a0.w;
            r0[4]=a1.x; r0[5]=a1.y; r0[6]=a1.z; r0[7]=a1.w;
            r0[8]=a2.x; r0[9]=a2.y; r0[10]=a2.z; r0[11]=a2.w;
            r0[12]=a3.x; r0[13]=a3.y; r0[14]=a3.z; r0[15]=a3.w;
            const float4* rq = (const float4*)&rbuf[((size_t)b * HW + p0 + 128) * 16];
            float4 c0 = rq[0], c1 = rq[1], c2 = rq[2], c3 = rq[3];
            r1[0]=c0.x; r1[1]=c0.y; r1[2]=c0.z; r1[3]=c0.w;
            r1[4]=c1.x; r1[5]=c1.y; r1[6]=c1.z; r1[7]=c1.w;
            r1[8]=c2.x; r1[9]=c2.y; r1[10]=c2.z; r1[11]=c2.w;
            r1[12]=c3.x; r1[13]=c3.y; r1[14]=c3.z; r1[15]=c3.w;
        }

        const float* wrow = wsp + g * KKN * RED;
        const float* brow = bsp + g * KKN;

        float acc0[RED], acc1[RED];
#pragma unroll
        for (int cc = 0; cc < RED; ++cc) { acc0[cc] = 0.f; acc1[cc] = 0.f; }

#pragma unroll 1
        for (int ir = 0; ir < 8; ++ir) {
            const unsigned* rowp = x1pad +
                ((size_t)(bg * PW + h0 + ir) * PW + w0) * 8;
#pragma unroll 1
            for (int j = 0; j < 7; ++j) {
                const unsigned* tp = rowp + (size_t)j * 8;
                uint4 A = *(const uint4*)tp;
                uint4 B = *(const uint4*)(tp + 4);
                float f[16];
                unpack_bf2(A.x, f[0], f[1]);   unpack_bf2(A.y, f[2], f[3]);
                unpack_bf2(A.z, f[4], f[5]);   unpack_bf2(A.w, f[6], f[7]);
                unpack_bf2(B.x, f[8], f[9]);   unpack_bf2(B.y, f[10], f[11]);
                unpack_bf2(B.z, f[12], f[13]); unpack_bf2(B.w, f[14], f[15]);
                if (ir < 7) {                   // tap i=ir for row h0
                    int k = ir * 7 + j;
                    const float* wk = wrow + k * RED;
                    float s = brow[k];
#pragma unroll
                    for (int jj = 0; jj < RED; ++jj) s += r0[jj] * wk[jj];
#pragma unroll
                    for (int cc = 0; cc < RED; ++cc) acc0[cc] += s * f[cc];
                }
                if (ir > 0) {                   // tap i=ir-1 for row h0+1
                    int k = (ir - 1) * 7 + j;
                    const float* wk = wrow + k * RED;
                    float s = brow[k];
#pragma unroll
                    for (int jj = 0; jj < RED; ++jj) s += r1[jj] * wk[jj];
#pragma unroll
                    for (int cc = 0; cc < RED; ++cc) acc1[cc] += s * f[cc];
                }
            }
        }

        unsigned pk0[8], pk1[8];
#pragma unroll
        for (int d = 0; d < 8; ++d) {
            int ch0 = g * RED + 2 * d, ch1 = ch0 + 1;
            float sA = par[PSC1_F + ch0], sB = par[PSC1_F + ch1];
            float hA = par[PSH1_F + ch0], hB = par[PSH1_F + ch1];
            pk0[d] = pack_bf2(gelu_f(sA * acc0[2 * d]     + hA),
                              gelu_f(sB * acc0[2 * d + 1] + hB));
            pk1[d] = pack_bf2(gelu_f(sA * acc1[2 * d]     + hA),
                              gelu_f(sB * acc1[2 * d + 1] + hB));
        }
        unsigned* xo0 = (unsigned*)&x2t[0][c][g * RED];
        *(uint4*)xo0       = make_uint4(pk0[0], pk0[1], pk0[2], pk0[3]);
        *(uint4*)(xo0 + 4) = make_uint4(pk0[4], pk0[5], pk0[6], pk0[7]);
        unsigned* xo1 = (unsigned*)&x2t[1][c][g * RED];
        *(uint4*)xo1       = make_uint4(pk1[0], pk1[1], pk1[2], pk1[3]);
        *(uint4*)(xo1 + 4) = make_uint4(pk1[4], pk1[5], pk1[6], pk1[7]);
    }

    __syncthreads();

    // ---- phase 2: out = gelu(sm*([x2|x].wcat) + shc), wave = 16 px, 2 passes
    {
        int lane = t & 63, wave = t >> 6;
        int m15  = lane & 15;
        int quad = lane >> 4;
        int pxl0 = wave * 16;

        const unsigned short* wcat = (const unsigned short*)(parb + BCAT);

        bf16x8 Bf[3][4];
#pragma unroll
        for (int kt = 0; kt < 3; ++kt)
#pragma unroll
            for (int nt = 0; nt < 4; ++nt)
                Bf[kt][nt] = *(const bf16x8*)&wcat[(nt * 16 + m15) * 96 + kt * 32 + quad * 8];

#pragma unroll 1
        for (int rr = 0; rr < 2; ++rr) {
            int pbase = (h0 + rr) * 128 + Cc * 64;

            bf16x8 Af[3];
            Af[0] = *(const bf16x8*)&x2t[rr][pxl0 + m15][quad * 8];
            Af[1] = *(const bf16x8*)&x2t[rr][pxl0 + m15][32 + quad * 8];
            Af[2] = *(const bf16x8*)&xbf[((size_t)(b * HW + pbase + pxl0 + m15)) * 32 + quad * 8];

            f32x4 acc[4];
#pragma unroll
            for (int nt = 0; nt < 4; ++nt) acc[nt] = (f32x4){0.f, 0.f, 0.f, 0.f};
#pragma unroll
            for (int kt = 0; kt < 3; ++kt)
#pragma unroll
                for (int nt = 0; nt < 4; ++nt)
                    acc[nt] = __builtin_amdgcn_mfma_f32_16x16x32_bf16(
                        Af[kt], Bf[kt][nt], acc[nt], 0, 0, 0);

#pragma unroll
            for (int nt = 0; nt < 4; ++nt) {
                int o = nt * 16 + m15;
                float smv = par[PSMV_F + o], sh = par[PSHC_F + o];
                float* op = out + (size_t)(b * COUT + o) * HW + pbase + pxl0 + quad * 4;
#pragma unroll
                for (int reg = 0; reg < 4; ++reg)
                    op[reg] = gelu_f(smv * acc[nt][reg] + sh);
            }
        }
    }
}

extern "C" void kernel_launch(void* const* d_in, const int* in_sizes, int n_in,
                              void* d_out, int out_size, void* d_ws, size_t ws_size,
                              hipStream_t stream) {
    const float* x    = (const float*)d_in[0];
    const float* w1   = (const float*)d_in[1];
    const float* wr   = (const float*)d_in[2];
    const float* gr   = (const float*)d_in[3];
    const float* br   = (const float*)d_in[4];
    const float* mr   = (const float*)d_in[5];
    const float* vr   = (const float*)d_in[6];
    const float* wsp  = (const float*)d_in[7];
    const float* bsp  = (const float*)d_in[8];
    const float* g1   = (const float*)d_in[9];
    const float* b1   = (const float*)d_in[10];
    const float* m1   = (const float*)d_in[11];
    const float* v1   = (const float*)d_in[12];
    const float* w2   = (const float*)d_in[13];
    const float* g2   = (const float*)d_in[14];
    const float* b2   = (const float*)d_in[15];
    const float* m2   = (const float*)d_in[16];
    const float* v2   = (const float*)d_in[17];
    const float* wm   = (const float*)d_in[18];
    const float* bmap = (const float*)d_in[19];
    const float* gm   = (const float*)d_in[20];
    const float* betam= (const float*)d_in[21];
    const float* mm   = (const float*)d_in[22];
    const float* vm   = (const float*)d_in[23];

    unsigned*       x1pad = (unsigned*)d_ws;
    float*          rbuf  = (float*)((char*)d_ws + OFF_RBUF);
    char*           parb  = (char*)d_ws + OFF_PAR;
    unsigned short* xbf   = (unsigned short*)((char*)d_ws + OFF_XBF);

    k1_all<<<NPXB + NZB + 1, 256, 0, stream>>>(
        x, w1, wr, gr, br, mr, vr, g1, b1, m1, v1,
        w2, g2, b2, m2, v2, wm, bmap, gm, betam, mm, vm,
        parb, x1pad, xbf, rbuf);
    k34_fused<<<Bsz * (HW / 128), 256, 0, stream>>>(
        x1pad, rbuf, wsp, bsp, parb, xbf, (float*)d_out);
}